// Round 7
// baseline (134.147 us; speedup 1.0000x reference)
//
#include <hip/hip_runtime.h>
#include <stdint.h>

#define B_ROWS 1024
#define FEAT   256
#define QSZ    32768
#define SHIFT  1024
#define QX     (QSZ - B_ROWS)   // 31744
#define NQB    256              // q-tiles of 128
#define MARGIN 8.0f             // bf16 scoring noise + key quantization headroom

typedef float v4f __attribute__((ext_vector_type(4)));
typedef short v8s __attribute__((ext_vector_type(8)));

// ---------- packed score keys: orderable(m)[31:15] | j[14:0] ----------
__device__ __forceinline__ uint32_t key_flip(uint32_t u) {
    return u ^ ((uint32_t)((int32_t)u >> 31) | 0x80000000u);
}
__device__ __forceinline__ float key_m(uint32_t k) {
    uint32_t u = k & 0xFFFF8000u;
    u = (u & 0x80000000u) ? (u ^ 0x80000000u) : ~u;
    return __uint_as_float(u);
}
__device__ __forceinline__ void k2_insert(uint32_t& k1, uint32_t& k2, uint32_t key) {
    uint32_t hi = max(k1, key); k1 = min(k1, key); k2 = min(k2, hi);
}
__device__ __forceinline__ uint2 k2_merge(uint2 a, uint2 b) {
    uint32_t hi = max(a.x, b.x);
    uint2 r; r.x = min(a.x, b.x); r.y = min(min(a.y, b.y), hi);
    return r;
}

// ---------- exact-score top2 (float + index tie-break, matches top_k) ----------
struct Top2 { float m1; int j1; float m2; int j2; };
__device__ __forceinline__ bool better(float ma, int ja, float mb, int jb) {
    return (ma < mb) || (ma == mb && ja < jb);
}
__device__ __forceinline__ void t2_insert(Top2& t, float m, int j) {
    if (better(m, j, t.m1, t.j1)) { t.m2 = t.m1; t.j2 = t.j1; t.m1 = m; t.j1 = j; }
    else if (better(m, j, t.m2, t.j2)) { t.m2 = m; t.j2 = j; }
}

__device__ __forceinline__ const float* q_row_ptr(int j, const float* x, const float* queue) {
    return (j < QX) ? (queue + (size_t)(j + SHIFT) * FEAT) : (x + (size_t)(j - QX) * FEAT);
}

__device__ __forceinline__ unsigned short f2bf(float f) {  // round-to-nearest-even
    uint32_t u = __float_as_uint(f);
    uint32_t r = u + 0x7FFFu + ((u >> 16) & 1u);
    return (unsigned short)(r >> 16);
}

__device__ __forceinline__ void lds_load16(const void* g, void* l) {
    __builtin_amdgcn_global_load_lds(
        (const __attribute__((address_space(1))) uint32_t*)g,
        (__attribute__((address_space(3))) uint32_t*)l, 16, 0, 0);
}

// ---------- kernel 1: q_bf (bf16 row-major, x tail included) + q2 (f32) ----------
__global__ __launch_bounds__(256) void convert_kernel(const float* __restrict__ x,
                                                      const float* __restrict__ queue,
                                                      unsigned short* __restrict__ q_bf,
                                                      float* __restrict__ q2) {
    int wave = threadIdx.x >> 6, lane = threadIdx.x & 63;
    int j = blockIdx.x * 4 + wave;
    const float4* row = (const float4*)q_row_ptr(j, x, queue);
    float4 v = row[lane];
    float s = v.x * v.x + v.y * v.y + v.z * v.z + v.w * v.w;
#pragma unroll
    for (int off = 32; off; off >>= 1) s += __shfl_xor(s, off, 64);
    if (lane == 0) q2[j] = s;
    ushort4 h;
    h.x = f2bf(v.x); h.y = f2bf(v.y); h.z = f2bf(v.z); h.w = f2bf(v.w);
    ((ushort4*)q_bf)[(size_t)j * 64 + lane] = h;
}

// ---------- kernel 2: ONE-BARRIER bf16 MFMA GEMM ----------
// B (x-tile) fragments held entirely in VGPRs (loaded from global; x is L2-resident).
// A (q-tile) staged once, full K=256, into 64 KB LDS via lds-DMA with XOR-(row&7)
// granule swizzle. Single __syncthreads; K-loop has zero barriers.
__global__ __launch_bounds__(256, 2) void nn_mfma(const unsigned short* __restrict__ q_bf,
                                                  const float* __restrict__ q2,
                                                  uint2* __restrict__ partials) {
    __shared__ unsigned short As[128 * 256];  // 64 KB: [row][swizzled 8-short granules]

    const int t    = threadIdx.x;
    const int w    = t >> 6, lane = t & 63;
    const int wm   = w >> 1, wn = w & 1;
    const int quad = lane >> 4, l16 = lane & 15;
    const int c3   = l16 & 7;

    // XCD-banded mapping (id&7 = XCD under round-robin dispatch; perf heuristic only)
    const int id = blockIdx.x;            // 0..2047
    const int s_ = id >> 3;               // 0..255
    const int gy = (id & 7) * 32 + (s_ & 31);  // q tile 0..255, banded per XCD
    const int gx = s_ >> 5;               // x tile 0..7

    const unsigned short* x_bf  = q_bf + (size_t)QX * FEAT;
    const unsigned short* aBase = q_bf + (size_t)gy * 128 * FEAT;
    const unsigned short* bBase = x_bf + (size_t)gx * 128 * FEAT;

    // ---- B fragments -> VGPRs (32 x dwordx4 per thread, issued first) ----
    v8s fb[4][8];
#pragma unroll
    for (int tn = 0; tn < 4; ++tn) {
        const unsigned short* brow = bBase + (size_t)(wn * 64 + tn * 16 + l16) * FEAT + quad * 8;
#pragma unroll
        for (int ks = 0; ks < 8; ++ks)
            fb[tn][ks] = *(const v8s*)(brow + ks * 32);
    }

    // ---- stage full A tile once (16 lds-DMA per thread) ----
    // wave-inst i covers rows w*32+2i, +1; lane L writes LDS granule L, sourcing
    // global granule (L&31)^(row&7) -> read side is conflict-free (<=2-way).
#pragma unroll
    for (int i = 0; i < 16; ++i) {
        int rowp = w * 32 + i * 2;
        int row  = rowp + (lane >> 5);
        int g    = (lane & 31) ^ (row & 7);
        lds_load16(aBase + (size_t)row * FEAT + g * 8, &As[rowp * 256]);
    }

    v4f acc[4][4];
#pragma unroll
    for (int a = 0; a < 4; ++a)
#pragma unroll
        for (int b = 0; b < 4; ++b) acc[a][b] = (v4f)0.0f;

    __syncthreads();  // the ONLY barrier: drains lds-DMA (and fb loads)

    // ---- K-loop: 8 steps x (4 ds_read_b128 + 16 MFMA), no barriers ----
#pragma unroll
    for (int ks = 0; ks < 8; ++ks) {
        const int gofs = (((ks * 4 + quad) ^ c3) << 4);
        v8s fa[4];
#pragma unroll
        for (int tm = 0; tm < 4; ++tm)
            fa[tm] = *(const v8s*)((const char*)As + (wm * 64 + tm * 16 + l16) * 512 + gofs);
#pragma unroll
        for (int tm = 0; tm < 4; ++tm)
#pragma unroll
            for (int tn = 0; tn < 4; ++tn)
                acc[tm][tn] = __builtin_amdgcn_mfma_f32_16x16x32_bf16(fa[tm], fb[tn][ks], acc[tm][tn], 0, 0, 0);
    }

    // ---- epilogue: keys = orderable(q2[row]-2*acc)|row; per-thread top2 per x-col ----
    const int jbase = gy * 128 + wm * 64 + quad * 4;
    float q2r[4][4];
#pragma unroll
    for (int tm = 0; tm < 4; ++tm) {
        v4f qq = *(const v4f*)(q2 + jbase + tm * 16);
#pragma unroll
        for (int r = 0; r < 4; ++r) q2r[tm][r] = qq[r];
    }

    uint2 best[4];
#pragma unroll
    for (int tn = 0; tn < 4; ++tn) {
        uint32_t k1 = 0xFFFFFFFFu, k2 = 0xFFFFFFFFu;
#pragma unroll
        for (int tm = 0; tm < 4; ++tm)
#pragma unroll
            for (int r = 0; r < 4; ++r) {
                float m = fmaf(-2.0f, acc[tm][tn][r], q2r[tm][r]);
                uint32_t u = key_flip(__float_as_uint(m));
                uint32_t key = (u & 0xFFFF8000u) | (uint32_t)(jbase + tm * 16 + r);
                k2_insert(k1, k2, key);
            }
        // merge across quads (same x-col lives in lanes l16, +16, +32, +48)
#pragma unroll
        for (int mask = 16; mask <= 32; mask <<= 1) {
            uint32_t o1 = __shfl_xor(k1, mask, 64);
            uint32_t o2 = __shfl_xor(k2, mask, 64);
            uint32_t hi = max(k1, o1);
            k1 = min(k1, o1);
            k2 = min(min(k2, o2), hi);
        }
        best[tn] = make_uint2(k1, k2);
    }
    __syncthreads();  // done reading As -> reuse as reduction scratch
    uint2* scr = (uint2*)As;  // [x-col 0..127][wm 0..1]
    if (quad == 0) {
#pragma unroll
        for (int tn = 0; tn < 4; ++tn)
            scr[(wn * 64 + tn * 16 + l16) * 2 + wm] = best[tn];
    }
    __syncthreads();
    if (t < 128) {
        uint2 r = k2_merge(scr[t * 2], scr[t * 2 + 1]);
        partials[(size_t)(gx * 128 + t) * NQB + gy] = r;
    }
}

// ---------- kernel 3: single-wave cutoff + exact f32 rescore + gather ----------
__global__ __launch_bounds__(64) void nn_finalize(const float* __restrict__ x,
                                                  const float* __restrict__ queue,
                                                  const float* __restrict__ q2,
                                                  const uint2* __restrict__ partials,
                                                  float* __restrict__ out) {
    __shared__ int list[64];
    __shared__ int s_cnt;

    const int i = blockIdx.x, lane = threadIdx.x;
    if (lane == 0) s_cnt = 0;

    const uint2* p = partials + (size_t)i * NQB;
    uint2 mine[4];
#pragma unroll
    for (int u = 0; u < 4; ++u) mine[u] = p[lane + 64 * u];
    uint2 a = k2_merge(k2_merge(mine[0], mine[1]), k2_merge(mine[2], mine[3]));
#pragma unroll
    for (int mask = 1; mask <= 32; mask <<= 1) {
        uint2 o;
        o.x = __shfl_xor(a.x, mask, 64);
        o.y = __shfl_xor(a.y, mask, 64);
        a = k2_merge(a, o);
    }
    float cutf = key_m(a.y) + MARGIN;
    uint32_t kcut = key_flip(__float_as_uint(cutf)) | 0x7FFFu;

#pragma unroll
    for (int u = 0; u < 4; ++u) {
        if (mine[u].x <= kcut) list[atomicAdd(&s_cnt, 1) & 63] = (int)(mine[u].x & 0x7FFFu);
        if (mine[u].y <= kcut) list[atomicAdd(&s_cnt, 1) & 63] = (int)(mine[u].y & 0x7FFFu);
    }
    __syncthreads();
    int n = min(s_cnt, 64);

    float4 xv = ((const float4*)(x + (size_t)i * FEAT))[lane];
    Top2 bst;
    bst.m1 = __builtin_inff(); bst.j1 = 0x7FFFFFFF;
    bst.m2 = __builtin_inff(); bst.j2 = 0x7FFFFFFF;
    for (int c = 0; c < n; ++c) {
        int j = list[c];
        float4 qv = ((const float4*)q_row_ptr(j, x, queue))[lane];
        float s = qv.x * xv.x + qv.y * xv.y + qv.z * xv.z + qv.w * xv.w;
#pragma unroll
        for (int off = 32; off; off >>= 1) s += __shfl_xor(s, off, 64);
        float m = q2[j] - 2.0f * s;   // lane-uniform exact score
        t2_insert(bst, m, j);
    }
    int j2 = bst.j2;  // second-nearest (nearest is self)
    float4 o = ((const float4*)q_row_ptr(j2, x, queue))[lane];
    ((float4*)(out + (size_t)i * FEAT))[lane] = o;
}

extern "C" void kernel_launch(void* const* d_in, const int* in_sizes, int n_in,
                              void* d_out, int out_size, void* d_ws, size_t ws_size,
                              hipStream_t stream) {
    const float* x     = (const float*)d_in[0];
    const float* queue = (const float*)d_in[1];

    unsigned short* q_bf     = (unsigned short*)d_ws;                    // 16 MB
    float*          q2       = (float*)((char*)d_ws + (16u << 20));      // 128 KB
    uint2*          partials = (uint2*)((char*)d_ws + (17u << 20));      // 2 MB

    convert_kernel<<<QSZ / 4, 256, 0, stream>>>(x, queue, q_bf, q2);
    nn_mfma<<<2048, 256, 0, stream>>>(q_bf, q2, partials);
    nn_finalize<<<B_ROWS, 64, 0, stream>>>(x, queue, q2, partials, (float*)d_out);
}